// Round 4
// baseline (352.634 us; speedup 1.0000x reference)
//
#include <hip/hip_runtime.h>
#include <stdint.h>

typedef unsigned short u16;
typedef __attribute__((ext_vector_type(8))) short short8;
typedef __attribute__((ext_vector_type(4))) float f32x4;

#define B_      16
#define L_      1024
#define H_      1024
#define G_      128
#define M_TOT   16368            // B*(L-1)
#define K_TOT   3072
#define OUT_SEG 2095104          // M_TOT*G_
#define KL_IDX  (4*OUT_SEG)
#define KL_BLOCKS 4092           // M_TOT / 4 exactly
#define NKT     48               // K_TOT / 64

// ws layout
#define WS_WT_OFF    0           // bf16 W'T [512][3072] = 3,145,728 B
#define WS_BIAS_OFF  3145728     // float[512]
#define WS_PART_OFF  3147776     // float[4092] block partials

__device__ inline u16 f2bf(float f) {
    union { float f; uint32_t u; } x; x.f = f;
    uint32_t u = x.u;
    return (u16)((u + 0x7fffu + ((u >> 16) & 1u)) >> 16);
}

__device__ inline void gload16(const void* g, void* l) {
    __builtin_amdgcn_global_load_lds(
        (const __attribute__((address_space(1))) void*)g,
        (__attribute__((address_space(3))) void*)l, 16, 0, 0);
}

// ---------------- prep: build W'T (bf16, [512][3072]) + bias[512] ------------
__global__ __launch_bounds__(256) void prep_kernel(
    const float* __restrict__ Wzm, const float* __restrict__ bzm,
    const float* __restrict__ Wzv, const float* __restrict__ bzv,
    const float* __restrict__ Wqm, const float* __restrict__ bqm,
    const float* __restrict__ Wqv, const float* __restrict__ bqv,
    u16* __restrict__ wt, float* __restrict__ bias)
{
    int n = blockIdx.x;                 // 0..511 (output column)
    int tid = threadIdx.x;
    const float* W; const float* bsrc; int g; int kmax;
    if (n < 128)      { W = Wzm; bsrc = bzm; g = n;       kmax = 2048; }
    else if (n < 256) { W = Wzv; bsrc = bzv; g = n - 128; kmax = 2048; }
    else if (n < 384) { W = Wqm; bsrc = bqm; g = n - 256; kmax = 3072; }
    else              { W = Wqv; bsrc = bqv; g = n - 384; kmax = 3072; }
    if (tid == 0) bias[n] = bsrc[g];
    #pragma unroll
    for (int i = 0; i < 12; ++i) {
        int k = i * 256 + tid;
        float v = (k < kmax) ? W[(size_t)k * G_ + g] : 0.0f;
        wt[(size_t)n * K_TOT + k] = f2bf(v);
    }
}

// ---------------- GEMM: out[m, 0:512] = ce @ W' + bias ----------------------
// BM=128, BN=128 (one output group per nb), BK=64, 4 waves (2x2 of 64x64).
// A: global f32x4 -> reg -> cvt_pk bf16 -> swizzled ds_write_b128 (SHORT live
//    range: load/write both BEFORE compute, so areg never spans the MFMAs).
// B: global_load_lds with source-preswizzled offsets (linear LDS dest).
// Swizzle: 16B-slot ^= (row&7); rows are 128B.
__global__ __launch_bounds__(256, 2) void gemm_kernel(
    const float* __restrict__ events, const float* __restrict__ contexts,
    const u16* __restrict__ wt, const float* __restrict__ bias,
    float* __restrict__ out)
{
    __shared__ u16 Ab[2][128 * 64];   // bf16 A tile, swizzled
    __shared__ u16 Bb[2][128 * 64];   // bf16 B tile, swizzled

    const int tid  = threadIdx.x;
    const int bid  = blockIdx.x;
    // XCD-aware swizzle: the 4 nb-blocks sharing an A panel land on one XCD.
    const int xcd  = bid & 7;
    const int nb   = (bid >> 3) & 3;
    const int mp   = xcd * 16 + (bid >> 5);
    const int m0   = mp * 128;

    const int lane = tid & 63;
    const int w    = tid >> 6;
    const int wm   = (w >> 1) * 64;
    const int wn   = (w & 1) * 64;
    const int lr   = lane & 15;
    const int kb   = (lane >> 4) * 8;      // u16 units within 32-wide K-chunk

    // ---- A staging setup: thread -> row r=tid>>1, half h=tid&1 (32 bf16) ----
    const int r = tid >> 1;
    const int h = tid & 1;
    int m = m0 + r; if (m > M_TOT - 1) m = M_TOT - 1;
    int bb = m / 1023;
    int tt = m - bb * 1023;
    const float* pa0 = events   + ((size_t)(bb * L_ + tt)) * H_;
    const float* pa1 = pa0 + H_;
    const float* pa2 = contexts + ((size_t)(bb * (L_ - 1) + tt)) * H_;
    // swizzled LDS u16 indices for the 4 ds_write_b128 of this thread
    int swrA[4];
    #pragma unroll
    for (int i = 0; i < 4; ++i)
        swrA[i] = r * 64 + ((((h << 2) + i) ^ (r & 7)) << 3);

    // ---- B staging setup: 4 gload_lds chunks/thread, source-preswizzled ----
    const u16* bB[4];
    #pragma unroll
    for (int it = 0; it < 4; ++it) {
        int c = it * 256 + tid;          // 0..1023
        int nloc = c >> 3;
        int co = (((c & 7) ^ (nloc & 7)) << 3);
        bB[it] = wt + (size_t)(nb * 128 + nloc) * K_TOT + co;
    }

    // ---- fragment read offsets (u16), swizzled ----
    int aoff[4][2], boff[4][2];
    #pragma unroll
    for (int i = 0; i < 4; ++i) {
        int row = wm + i * 16 + lr;
        int nn  = wn + i * 16 + lr;
        #pragma unroll
        for (int ks = 0; ks < 2; ++ks) {
            aoff[i][ks] = row * 64 + ((ks * 32 + kb) ^ ((row & 7) << 3));
            boff[i][ks] = nn  * 64 + ((ks * 32 + kb) ^ ((nn  & 7) << 3));
        }
    }

    f32x4 acc[4][4];
    #pragma unroll
    for (int i = 0; i < 4; ++i)
        #pragma unroll
        for (int j = 0; j < 4; ++j)
            acc[i][j] = (f32x4){0.f, 0.f, 0.f, 0.f};

    f32x4 areg[8];

    auto loadA = [&](int kt) {
        int k0 = kt * 64;
        int rg = k0 >> 10;
        int kq = (k0 & 1023) + h * 32;
        const float* s = (rg == 0) ? pa0 : (rg == 1 ? pa1 : pa2);
        s += kq;
        #pragma unroll
        for (int i = 0; i < 8; ++i) areg[i] = *(const f32x4*)(s + i * 4);
    };
    auto writeA = [&](int buf) {
        #pragma unroll
        for (int i = 0; i < 4; ++i) {
            union { short8 s; uint32_t u[4]; } wv;
            asm("v_cvt_pk_bf16_f32 %0, %1, %2" : "=v"(wv.u[0]) : "v"(areg[2*i][0]), "v"(areg[2*i][1]));
            asm("v_cvt_pk_bf16_f32 %0, %1, %2" : "=v"(wv.u[1]) : "v"(areg[2*i][2]), "v"(areg[2*i][3]));
            asm("v_cvt_pk_bf16_f32 %0, %1, %2" : "=v"(wv.u[2]) : "v"(areg[2*i+1][0]), "v"(areg[2*i+1][1]));
            asm("v_cvt_pk_bf16_f32 %0, %1, %2" : "=v"(wv.u[3]) : "v"(areg[2*i+1][2]), "v"(areg[2*i+1][3]));
            *(short8*)&Ab[buf][swrA[i]] = wv.s;
        }
    };
    auto stageB = [&](int buf, int kt) {
        int k0 = kt * 64;
        #pragma unroll
        for (int it = 0; it < 4; ++it)
            gload16(bB[it] + k0, &Bb[buf][(it * 256 + tid) * 8]);
    };
    auto compute = [&](int buf) {
        #pragma unroll
        for (int ks = 0; ks < 2; ++ks) {
            short8 a[4], bf[4];
            #pragma unroll
            for (int i = 0; i < 4; ++i)
                a[i] = *(const short8*)&Ab[buf][aoff[i][ks]];
            #pragma unroll
            for (int j = 0; j < 4; ++j)
                bf[j] = *(const short8*)&Bb[buf][boff[j][ks]];
            #pragma unroll
            for (int i = 0; i < 4; ++i)
                #pragma unroll
                for (int j = 0; j < 4; ++j)
                    acc[i][j] = __builtin_amdgcn_mfma_f32_16x16x32_bf16(
                        a[i], bf[j], acc[i][j], 0, 0, 0);
        }
    };

    // prologue: fill buffer 0
    stageB(0, 0);
    loadA(0);
    writeA(0);
    __syncthreads();

    int cur = 0;
    for (int kt = 0; kt < NKT; ++kt) {
        if (kt + 1 < NKT) {
            loadA(kt + 1);             // A global->reg for next tile (issue)
            stageB(cur ^ 1, kt + 1);   // async B loads for next tile
            writeA(cur ^ 1);           // wait areg, cvt, swizzled ds_write;
                                       // areg DIES here (before any MFMA)
        }
        compute(cur);                  // ds_read + MFMA on current tile
        __syncthreads();
        cur ^= 1;
    }

    // epilogue: C row = wm + i*16 + (lane>>4)*4 + r ; col = wn + j*16 + (lane&15)
    const float* bptr = bias + nb * 128;
    float* obase = out + (size_t)nb * OUT_SEG;
    #pragma unroll
    for (int i = 0; i < 4; ++i) {
        int mloc = wm + i * 16 + (lane >> 4) * 4;
        #pragma unroll
        for (int j = 0; j < 4; ++j) {
            int g = wn + j * 16 + lr;
            float bv = bptr[g];
            #pragma unroll
            for (int rr = 0; rr < 4; ++rr) {
                int mo = m0 + mloc + rr;
                if (mo < M_TOT) obase[(size_t)mo * G_ + g] = acc[i][j][rr] + bv;
            }
        }
    }
}

// ---------------- KL reduction: stage 1 (per-block partials, no atomics) -----
__global__ __launch_bounds__(256) void kl_kernel(const float* __restrict__ out,
                                                 float* __restrict__ partial)
{
    int wid  = threadIdx.x >> 6;
    int row  = blockIdx.x * 4 + wid;        // M_TOT = 4092*4 exactly
    int lane = threadIdx.x & 63;
    const float* zm  = out;
    const float* zlv = out + OUT_SEG;
    const float* qm  = out + (size_t)2 * OUT_SEG;
    const float* qlv = out + (size_t)3 * OUT_SEG;
    size_t base = (size_t)row * G_;
    float s = 0.f;
    #pragma unroll
    for (int hh = 0; hh < 2; ++hh) {
        int g = lane + hh * 64;
        float a = zm[base + g], b = zlv[base + g];
        float c = qm[base + g], d = qlv[base + g];
        float diff = a - c;
        s += d - b + (__expf(b) + diff * diff) * __expf(-d) - 1.0f;
    }
    #pragma unroll
    for (int off = 32; off > 0; off >>= 1)
        s += __shfl_down(s, off);
    __shared__ float pw[4];
    if (lane == 0) pw[wid] = s;
    __syncthreads();
    if (threadIdx.x == 0)
        partial[blockIdx.x] = pw[0] + pw[1] + pw[2] + pw[3];
}

// ---------------- KL reduction: stage 2 --------------------------------------
__global__ __launch_bounds__(256) void kl_final(const float* __restrict__ partial,
                                                float* __restrict__ out)
{
    float s = 0.f;
    for (int i = threadIdx.x; i < KL_BLOCKS; i += 256) s += partial[i];
    #pragma unroll
    for (int off = 32; off > 0; off >>= 1)
        s += __shfl_down(s, off);
    __shared__ float pw[4];
    int wid = threadIdx.x >> 6;
    int lane = threadIdx.x & 63;
    if (lane == 0) pw[wid] = s;
    __syncthreads();
    if (threadIdx.x == 0)
        out[KL_IDX] = 0.5f * (pw[0] + pw[1] + pw[2] + pw[3]) / (float)M_TOT;
}

// ---------------- launcher ----------------------------------------------------
extern "C" void kernel_launch(void* const* d_in, const int* in_sizes, int n_in,
                              void* d_out, int out_size, void* d_ws, size_t ws_size,
                              hipStream_t stream)
{
    const float* events   = (const float*)d_in[0];
    const float* contexts = (const float*)d_in[1];
    const float* Wzm = (const float*)d_in[2];
    const float* bzm = (const float*)d_in[3];
    const float* Wzv = (const float*)d_in[4];
    const float* bzv = (const float*)d_in[5];
    const float* Wqm = (const float*)d_in[6];
    const float* bqm = (const float*)d_in[7];
    const float* Wqv = (const float*)d_in[8];
    const float* bqv = (const float*)d_in[9];
    float* out = (float*)d_out;

    u16*   wt      = (u16*)((char*)d_ws + WS_WT_OFF);
    float* bias    = (float*)((char*)d_ws + WS_BIAS_OFF);
    float* partial = (float*)((char*)d_ws + WS_PART_OFF);

    prep_kernel<<<512, 256, 0, stream>>>(Wzm, bzm, Wzv, bzv, Wqm, bqm, Wqv, bqv,
                                         wt, bias);
    gemm_kernel<<<512, 256, 0, stream>>>(events, contexts, wt, bias, out);
    kl_kernel<<<KL_BLOCKS, 256, 0, stream>>>(out, partial);
    kl_final<<<1, 256, 0, stream>>>(partial, out);
}

// Round 5
// 163.252 us; speedup vs baseline: 2.1601x; 2.1601x over previous
//
#include <hip/hip_runtime.h>
#include <stdint.h>

typedef unsigned short u16;
typedef __attribute__((ext_vector_type(8))) short short8;
typedef __attribute__((ext_vector_type(4))) float f32x4;

#define B_      16
#define L_      1024
#define H_      1024
#define G_      128
#define M_TOT   16368            // B*(L-1)
#define K_TOT   3072
#define OUT_SEG 2095104          // M_TOT*G_
#define KL_IDX  (4*OUT_SEG)
#define KL_BLOCKS 4092           // M_TOT / 4 exactly
#define NKT     48               // K_TOT / 64

// ws layout
#define WS_WT_OFF    0           // bf16 W'T [512][3072] = 3,145,728 B
#define WS_BIAS_OFF  3145728     // float[512]
#define WS_PART_OFF  3147776     // float[4092] block partials

__device__ inline u16 f2bf(float f) {
    union { float f; uint32_t u; } x; x.f = f;
    uint32_t u = x.u;
    return (u16)((u + 0x7fffu + ((u >> 16) & 1u)) >> 16);
}

__device__ inline void gload16(const void* g, void* l) {
    __builtin_amdgcn_global_load_lds(
        (const __attribute__((address_space(1))) void*)g,
        (__attribute__((address_space(3))) void*)l, 16, 0, 0);
}

// ---------------- prep: build W'T (bf16, [512][3072]) + bias[512] ------------
__global__ __launch_bounds__(256) void prep_kernel(
    const float* __restrict__ Wzm, const float* __restrict__ bzm,
    const float* __restrict__ Wzv, const float* __restrict__ bzv,
    const float* __restrict__ Wqm, const float* __restrict__ bqm,
    const float* __restrict__ Wqv, const float* __restrict__ bqv,
    u16* __restrict__ wt, float* __restrict__ bias)
{
    int n = blockIdx.x;                 // 0..511 (output column)
    int tid = threadIdx.x;
    const float* W; const float* bsrc; int g; int kmax;
    if (n < 128)      { W = Wzm; bsrc = bzm; g = n;       kmax = 2048; }
    else if (n < 256) { W = Wzv; bsrc = bzv; g = n - 128; kmax = 2048; }
    else if (n < 384) { W = Wqm; bsrc = bqm; g = n - 256; kmax = 3072; }
    else              { W = Wqv; bsrc = bqv; g = n - 384; kmax = 3072; }
    if (tid == 0) bias[n] = bsrc[g];
    #pragma unroll
    for (int i = 0; i < 12; ++i) {
        int k = i * 256 + tid;
        float v = (k < kmax) ? W[(size_t)k * G_ + g] : 0.0f;
        wt[(size_t)n * K_TOT + k] = f2bf(v);
    }
}

// ---------------- GEMM: out[m, 0:512] = ce @ W' + bias ----------------------
// BM=128, BN=128 (one output group per nb), BK=64, 4 waves (2x2 of 64x64).
// A: global f32x4 -> NAMED regs (no array, no lambda: avoids scratch alloca)
//    -> cvt_pk bf16 -> swizzled ds_write_b128.
// B: global_load_lds with source-preswizzled offsets (linear LDS dest).
// Swizzle: 16B-slot ^= (row&7); rows are 128B.
__global__ __launch_bounds__(256, 2) void gemm_kernel(
    const float* __restrict__ events, const float* __restrict__ contexts,
    const u16* __restrict__ wt, const float* __restrict__ bias,
    float* __restrict__ out)
{
    __shared__ u16 Ab[2][128 * 64];   // bf16 A tile, swizzled
    __shared__ u16 Bb[2][128 * 64];   // bf16 B tile, swizzled

    const int tid  = threadIdx.x;
    const int bid  = blockIdx.x;
    // XCD-aware swizzle: the 4 nb-blocks sharing an A panel land on one XCD.
    const int xcd  = bid & 7;
    const int nb   = (bid >> 3) & 3;
    const int mp   = xcd * 16 + (bid >> 5);
    const int m0   = mp * 128;

    const int lane = tid & 63;
    const int w    = tid >> 6;
    const int wm   = (w >> 1) * 64;
    const int wn   = (w & 1) * 64;
    const int lr   = lane & 15;
    const int kb   = (lane >> 4) * 8;      // u16 units within 32-wide K-chunk

    // ---- A staging setup: thread -> row r=tid>>1, half h=tid&1 (32 bf16) ----
    const int r = tid >> 1;
    const int h = tid & 1;
    int m = m0 + r; if (m > M_TOT - 1) m = M_TOT - 1;
    int bb = m / 1023;
    int tt = m - bb * 1023;
    const float* pa0 = events   + ((size_t)(bb * L_ + tt)) * H_;
    const float* pa1 = pa0 + H_;
    const float* pa2 = contexts + ((size_t)(bb * (L_ - 1) + tt)) * H_;
    // swizzled LDS u16 indices for the 4 ds_write_b128 of this thread
    const int swr0 = r * 64 + ((((h << 2) + 0) ^ (r & 7)) << 3);
    const int swr1 = r * 64 + ((((h << 2) + 1) ^ (r & 7)) << 3);
    const int swr2 = r * 64 + ((((h << 2) + 2) ^ (r & 7)) << 3);
    const int swr3 = r * 64 + ((((h << 2) + 3) ^ (r & 7)) << 3);

    // ---- B staging setup: 4 gload_lds chunks/thread, source-preswizzled ----
    const u16* bB[4];
    #pragma unroll
    for (int it = 0; it < 4; ++it) {
        int c = it * 256 + tid;          // 0..1023
        int nloc = c >> 3;
        int co = (((c & 7) ^ (nloc & 7)) << 3);
        bB[it] = wt + (size_t)(nb * 128 + nloc) * K_TOT + co;
    }

    // ---- fragment read offsets (u16), swizzled ----
    int aoff[4][2], boff[4][2];
    #pragma unroll
    for (int i = 0; i < 4; ++i) {
        int row = wm + i * 16 + lr;
        int nn  = wn + i * 16 + lr;
        #pragma unroll
        for (int ks = 0; ks < 2; ++ks) {
            aoff[i][ks] = row * 64 + ((ks * 32 + kb) ^ ((row & 7) << 3));
            boff[i][ks] = nn  * 64 + ((ks * 32 + kb) ^ ((nn  & 7) << 3));
        }
    }

    f32x4 acc[4][4];
    #pragma unroll
    for (int i = 0; i < 4; ++i)
        #pragma unroll
        for (int j = 0; j < 4; ++j)
            acc[i][j] = (f32x4){0.f, 0.f, 0.f, 0.f};

    auto stageB = [&](int buf, int kt) {
        int k0 = kt * 64;
        #pragma unroll
        for (int it = 0; it < 4; ++it)
            gload16(bB[it] + k0, &Bb[buf][(it * 256 + tid) * 8]);
    };
    auto compute = [&](int buf) {
        #pragma unroll
        for (int ks = 0; ks < 2; ++ks) {
            short8 a[4], bf[4];
            #pragma unroll
            for (int i = 0; i < 4; ++i)
                a[i] = *(const short8*)&Ab[buf][aoff[i][ks]];
            #pragma unroll
            for (int j = 0; j < 4; ++j)
                bf[j] = *(const short8*)&Bb[buf][boff[j][ks]];
            #pragma unroll
            for (int i = 0; i < 4; ++i)
                #pragma unroll
                for (int j = 0; j < 4; ++j)
                    acc[i][j] = __builtin_amdgcn_mfma_f32_16x16x32_bf16(
                        a[i], bf[j], acc[i][j], 0, 0, 0);
        }
    };

    // A stage: global loads into NAMED regs, B issue between, cvt+write after.
    // (macro, not lambda: no address-taken array -> no scratch)
#define STAGE_A_BODY(BUF, KT, DO_B, BBUF)                                      \
    {                                                                          \
        int k0 = (KT) * 64;                                                    \
        int rg = k0 >> 10;                                                     \
        int kq = (k0 & 1023) + h * 32;                                         \
        const float* s = (rg == 0) ? pa0 : (rg == 1 ? pa1 : pa2);              \
        s += kq;                                                               \
        f32x4 A0 = *(const f32x4*)(s +  0);                                    \
        f32x4 A1 = *(const f32x4*)(s +  4);                                    \
        f32x4 A2 = *(const f32x4*)(s +  8);                                    \
        f32x4 A3 = *(const f32x4*)(s + 12);                                    \
        f32x4 A4 = *(const f32x4*)(s + 16);                                    \
        f32x4 A5 = *(const f32x4*)(s + 20);                                    \
        f32x4 A6 = *(const f32x4*)(s + 24);                                    \
        f32x4 A7 = *(const f32x4*)(s + 28);                                    \
        if (DO_B) stageB(BBUF, (KT));                                          \
        union { short8 v; uint32_t u[4]; } W0, W1, W2, W3;                     \
        asm("v_cvt_pk_bf16_f32 %0, %1, %2" : "=v"(W0.u[0]) : "v"(A0[0]), "v"(A0[1])); \
        asm("v_cvt_pk_bf16_f32 %0, %1, %2" : "=v"(W0.u[1]) : "v"(A0[2]), "v"(A0[3])); \
        asm("v_cvt_pk_bf16_f32 %0, %1, %2" : "=v"(W0.u[2]) : "v"(A1[0]), "v"(A1[1])); \
        asm("v_cvt_pk_bf16_f32 %0, %1, %2" : "=v"(W0.u[3]) : "v"(A1[2]), "v"(A1[3])); \
        asm("v_cvt_pk_bf16_f32 %0, %1, %2" : "=v"(W1.u[0]) : "v"(A2[0]), "v"(A2[1])); \
        asm("v_cvt_pk_bf16_f32 %0, %1, %2" : "=v"(W1.u[1]) : "v"(A2[2]), "v"(A2[3])); \
        asm("v_cvt_pk_bf16_f32 %0, %1, %2" : "=v"(W1.u[2]) : "v"(A3[0]), "v"(A3[1])); \
        asm("v_cvt_pk_bf16_f32 %0, %1, %2" : "=v"(W1.u[3]) : "v"(A3[2]), "v"(A3[3])); \
        asm("v_cvt_pk_bf16_f32 %0, %1, %2" : "=v"(W2.u[0]) : "v"(A4[0]), "v"(A4[1])); \
        asm("v_cvt_pk_bf16_f32 %0, %1, %2" : "=v"(W2.u[1]) : "v"(A4[2]), "v"(A4[3])); \
        asm("v_cvt_pk_bf16_f32 %0, %1, %2" : "=v"(W2.u[2]) : "v"(A5[0]), "v"(A5[1])); \
        asm("v_cvt_pk_bf16_f32 %0, %1, %2" : "=v"(W2.u[3]) : "v"(A5[2]), "v"(A5[3])); \
        asm("v_cvt_pk_bf16_f32 %0, %1, %2" : "=v"(W3.u[0]) : "v"(A6[0]), "v"(A6[1])); \
        asm("v_cvt_pk_bf16_f32 %0, %1, %2" : "=v"(W3.u[1]) : "v"(A6[2]), "v"(A6[3])); \
        asm("v_cvt_pk_bf16_f32 %0, %1, %2" : "=v"(W3.u[2]) : "v"(A7[0]), "v"(A7[1])); \
        asm("v_cvt_pk_bf16_f32 %0, %1, %2" : "=v"(W3.u[3]) : "v"(A7[2]), "v"(A7[3])); \
        *(short8*)&Ab[BUF][swr0] = W0.v;                                       \
        *(short8*)&Ab[BUF][swr1] = W1.v;                                       \
        *(short8*)&Ab[BUF][swr2] = W2.v;                                       \
        *(short8*)&Ab[BUF][swr3] = W3.v;                                       \
    }

    // prologue: fill buffer 0
    STAGE_A_BODY(0, 0, 1, 0);
    __syncthreads();

    int cur = 0;
    for (int kt = 0; kt < NKT; ++kt) {
        if (kt + 1 < NKT) {
            // A loads issued first (oldest), B gload_lds after -> the cvt's
            // wait leaves B loads in flight.
            STAGE_A_BODY(cur ^ 1, kt + 1, 1, cur ^ 1);
        }
        compute(cur);                  // ds_read + MFMA on current tile
        __syncthreads();
        cur ^= 1;
    }

    // epilogue: C row = wm + i*16 + (lane>>4)*4 + r ; col = wn + j*16 + (lane&15)
    const float* bptr = bias + nb * 128;
    float* obase = out + (size_t)nb * OUT_SEG;
    #pragma unroll
    for (int i = 0; i < 4; ++i) {
        int mloc = wm + i * 16 + (lane >> 4) * 4;
        #pragma unroll
        for (int j = 0; j < 4; ++j) {
            int g = wn + j * 16 + lr;
            float bv = bptr[g];
            #pragma unroll
            for (int rr = 0; rr < 4; ++rr) {
                int mo = m0 + mloc + rr;
                if (mo < M_TOT) obase[(size_t)mo * G_ + g] = acc[i][j][rr] + bv;
            }
        }
    }
#undef STAGE_A_BODY
}

// ---------------- KL reduction: stage 1 (per-block partials, no atomics) -----
__global__ __launch_bounds__(256) void kl_kernel(const float* __restrict__ out,
                                                 float* __restrict__ partial)
{
    int wid  = threadIdx.x >> 6;
    int row  = blockIdx.x * 4 + wid;        // M_TOT = 4092*4 exactly
    int lane = threadIdx.x & 63;
    const float* zm  = out;
    const float* zlv = out + OUT_SEG;
    const float* qm  = out + (size_t)2 * OUT_SEG;
    const float* qlv = out + (size_t)3 * OUT_SEG;
    size_t base = (size_t)row * G_;
    float s = 0.f;
    #pragma unroll
    for (int hh = 0; hh < 2; ++hh) {
        int g = lane + hh * 64;
        float a = zm[base + g], b = zlv[base + g];
        float c = qm[base + g], d = qlv[base + g];
        float diff = a - c;
        s += d - b + (__expf(b) + diff * diff) * __expf(-d) - 1.0f;
    }
    #pragma unroll
    for (int off = 32; off > 0; off >>= 1)
        s += __shfl_down(s, off);
    __shared__ float pw[4];
    if (lane == 0) pw[wid] = s;
    __syncthreads();
    if (threadIdx.x == 0)
        partial[blockIdx.x] = pw[0] + pw[1] + pw[2] + pw[3];
}

// ---------------- KL reduction: stage 2 --------------------------------------
__global__ __launch_bounds__(256) void kl_final(const float* __restrict__ partial,
                                                float* __restrict__ out)
{
    float s = 0.f;
    for (int i = threadIdx.x; i < KL_BLOCKS; i += 256) s += partial[i];
    #pragma unroll
    for (int off = 32; off > 0; off >>= 1)
        s += __shfl_down(s, off);
    __shared__ float pw[4];
    int wid = threadIdx.x >> 6;
    int lane = threadIdx.x & 63;
    if (lane == 0) pw[wid] = s;
    __syncthreads();
    if (threadIdx.x == 0)
        out[KL_IDX] = 0.5f * (pw[0] + pw[1] + pw[2] + pw[3]) / (float)M_TOT;
}

// ---------------- launcher ----------------------------------------------------
extern "C" void kernel_launch(void* const* d_in, const int* in_sizes, int n_in,
                              void* d_out, int out_size, void* d_ws, size_t ws_size,
                              hipStream_t stream)
{
    const float* events   = (const float*)d_in[0];
    const float* contexts = (const float*)d_in[1];
    const float* Wzm = (const float*)d_in[2];
    const float* bzm = (const float*)d_in[3];
    const float* Wzv = (const float*)d_in[4];
    const float* bzv = (const float*)d_in[5];
    const float* Wqm = (const float*)d_in[6];
    const float* bqm = (const float*)d_in[7];
    const float* Wqv = (const float*)d_in[8];
    const float* bqv = (const float*)d_in[9];
    float* out = (float*)d_out;

    u16*   wt      = (u16*)((char*)d_ws + WS_WT_OFF);
    float* bias    = (float*)((char*)d_ws + WS_BIAS_OFF);
    float* partial = (float*)((char*)d_ws + WS_PART_OFF);

    prep_kernel<<<512, 256, 0, stream>>>(Wzm, bzm, Wzv, bzv, Wqm, bqm, Wqv, bqv,
                                         wt, bias);
    gemm_kernel<<<512, 256, 0, stream>>>(events, contexts, wt, bias, out);
    kl_kernel<<<KL_BLOCKS, 256, 0, stream>>>(out, partial);
    kl_final<<<1, 256, 0, stream>>>(partial, out);
}

// Round 6
// 156.522 us; speedup vs baseline: 2.2529x; 1.0430x over previous
//
#include <hip/hip_runtime.h>
#include <stdint.h>

typedef unsigned short u16;
typedef __attribute__((ext_vector_type(8))) short short8;
typedef __attribute__((ext_vector_type(4))) float f32x4;

#define B_      16
#define L_      1024
#define H_      1024
#define G_      128
#define M_TOT   16368            // B*(L-1)
#define K_TOT   3072
#define OUT_SEG 2095104          // M_TOT*G_
#define KL_IDX  (4*OUT_SEG)
#define KL_BLOCKS 4092           // M_TOT / 4 exactly
#define NKT     48               // K_TOT / 64

// ws layout
#define WS_WT_OFF    0           // bf16 W'T [512][3072] = 3,145,728 B
#define WS_BIAS_OFF  3145728     // float[512]
#define WS_PART_OFF  3147776     // float[4092] block partials

__device__ inline u16 f2bf(float f) {
    union { float f; uint32_t u; } x; x.f = f;
    uint32_t u = x.u;
    return (u16)((u + 0x7fffu + ((u >> 16) & 1u)) >> 16);
}

__device__ inline void gload16(const void* g, void* l) {
    __builtin_amdgcn_global_load_lds(
        (const __attribute__((address_space(1))) void*)g,
        (__attribute__((address_space(3))) void*)l, 16, 0, 0);
}

// ---------------- prep: build W'T (bf16, [512][3072]) + bias[512] ------------
__global__ __launch_bounds__(256) void prep_kernel(
    const float* __restrict__ Wzm, const float* __restrict__ bzm,
    const float* __restrict__ Wzv, const float* __restrict__ bzv,
    const float* __restrict__ Wqm, const float* __restrict__ bqm,
    const float* __restrict__ Wqv, const float* __restrict__ bqv,
    u16* __restrict__ wt, float* __restrict__ bias)
{
    int n = blockIdx.x;                 // 0..511 (output column)
    int tid = threadIdx.x;
    const float* W; const float* bsrc; int g; int kmax;
    if (n < 128)      { W = Wzm; bsrc = bzm; g = n;       kmax = 2048; }
    else if (n < 256) { W = Wzv; bsrc = bzv; g = n - 128; kmax = 2048; }
    else if (n < 384) { W = Wqm; bsrc = bqm; g = n - 256; kmax = 3072; }
    else              { W = Wqv; bsrc = bqv; g = n - 384; kmax = 3072; }
    if (tid == 0) bias[n] = bsrc[g];
    #pragma unroll
    for (int i = 0; i < 12; ++i) {
        int k = i * 256 + tid;
        float v = (k < kmax) ? W[(size_t)k * G_ + g] : 0.0f;
        wt[(size_t)n * K_TOT + k] = f2bf(v);
    }
}

// ---------------- GEMM: out[m, 0:512] = ce @ W' + bias ----------------------
// BM=128, BN=128, BK=64, 4 waves (2x2 of 64x64).
// Pipeline (per phase t):
//   issue A global loads for t+2 (named regs P/Q, 2-deep)
//   issue B global_load_lds for t+1 (source-preswizzled)
//   compute(t)   [ds_read + 32 MFMA]
//   cvt+swizzled ds_write of A for t+1 (regs loaded LAST phase: zero wait)
//   barrier
__global__ __launch_bounds__(256, 2) void gemm_kernel(
    const float* __restrict__ events, const float* __restrict__ contexts,
    const u16* __restrict__ wt, const float* __restrict__ bias,
    float* __restrict__ out)
{
    __shared__ u16 Ab[2][128 * 64];   // bf16 A tile, swizzled
    __shared__ u16 Bb[2][128 * 64];   // bf16 B tile, swizzled

    const int tid  = threadIdx.x;
    const int bid  = blockIdx.x;
    // XCD-aware swizzle: the 4 nb-blocks sharing an A panel land on one XCD.
    const int xcd  = bid & 7;
    const int nb   = (bid >> 3) & 3;
    const int mp   = xcd * 16 + (bid >> 5);
    const int m0   = mp * 128;

    const int lane = tid & 63;
    const int w    = tid >> 6;
    const int wm   = (w >> 1) * 64;
    const int wn   = (w & 1) * 64;
    const int lr   = lane & 15;
    const int kb   = (lane >> 4) * 8;      // u16 units within 32-wide K-chunk

    // ---- A staging setup: thread -> row r=tid>>1, half h=tid&1 (32 bf16) ----
    const int r = tid >> 1;
    const int h = tid & 1;
    int m = m0 + r; if (m > M_TOT - 1) m = M_TOT - 1;
    int bb = m / 1023;
    int tt = m - bb * 1023;
    const float* pa0 = events   + ((size_t)(bb * L_ + tt)) * H_;
    const float* pa1 = pa0 + H_;
    const float* pa2 = contexts + ((size_t)(bb * (L_ - 1) + tt)) * H_;
    // swizzled LDS u16 indices for the 4 ds_write_b128 of this thread
    const int swr0 = r * 64 + ((((h << 2) + 0) ^ (r & 7)) << 3);
    const int swr1 = r * 64 + ((((h << 2) + 1) ^ (r & 7)) << 3);
    const int swr2 = r * 64 + ((((h << 2) + 2) ^ (r & 7)) << 3);
    const int swr3 = r * 64 + ((((h << 2) + 3) ^ (r & 7)) << 3);

    // ---- B staging setup: 4 gload_lds chunks/thread, source-preswizzled ----
    const u16* bB[4];
    #pragma unroll
    for (int it = 0; it < 4; ++it) {
        int c = it * 256 + tid;          // 0..1023
        int nloc = c >> 3;
        int co = (((c & 7) ^ (nloc & 7)) << 3);
        bB[it] = wt + (size_t)(nb * 128 + nloc) * K_TOT + co;
    }

    // ---- fragment read offsets (u16), swizzled ----
    int aoff[4][2], boff[4][2];
    #pragma unroll
    for (int i = 0; i < 4; ++i) {
        int row = wm + i * 16 + lr;
        int nn  = wn + i * 16 + lr;
        #pragma unroll
        for (int ks = 0; ks < 2; ++ks) {
            aoff[i][ks] = row * 64 + ((ks * 32 + kb) ^ ((row & 7) << 3));
            boff[i][ks] = nn  * 64 + ((ks * 32 + kb) ^ ((nn  & 7) << 3));
        }
    }

    f32x4 acc[4][4];
    #pragma unroll
    for (int i = 0; i < 4; ++i)
        #pragma unroll
        for (int j = 0; j < 4; ++j)
            acc[i][j] = (f32x4){0.f, 0.f, 0.f, 0.f};

    auto stageB = [&](int buf, int kt) {
        int k0 = kt * 64;
        #pragma unroll
        for (int it = 0; it < 4; ++it)
            gload16(bB[it] + k0, &Bb[buf][(it * 256 + tid) * 8]);
    };
    auto compute = [&](int buf) {
        #pragma unroll
        for (int ks = 0; ks < 2; ++ks) {
            short8 a[4], bf[4];
            #pragma unroll
            for (int i = 0; i < 4; ++i)
                a[i] = *(const short8*)&Ab[buf][aoff[i][ks]];
            #pragma unroll
            for (int j = 0; j < 4; ++j)
                bf[j] = *(const short8*)&Bb[buf][boff[j][ks]];
            #pragma unroll
            for (int i = 0; i < 4; ++i)
                #pragma unroll
                for (int j = 0; j < 4; ++j)
                    acc[i][j] = __builtin_amdgcn_mfma_f32_16x16x32_bf16(
                        a[i], bf[j], acc[i][j], 0, 0, 0);
        }
    };

    // Named A-staging registers (two sets, 2-phase-deep pipeline)
    f32x4 P0, P1, P2, P3, P4, P5, P6, P7;
    f32x4 Q0, Q1, Q2, Q3, Q4, Q5, Q6, Q7;

#define LOADA(p, KT)                                                           \
    {                                                                          \
        int k0_ = (KT) * 64;                                                   \
        int rg_ = k0_ >> 10;                                                   \
        int kq_ = (k0_ & 1023) + h * 32;                                       \
        const float* s_ = (rg_ == 0) ? pa0 : (rg_ == 1 ? pa1 : pa2);           \
        s_ += kq_;                                                             \
        p##0 = *(const f32x4*)(s_ +  0);                                       \
        p##1 = *(const f32x4*)(s_ +  4);                                       \
        p##2 = *(const f32x4*)(s_ +  8);                                       \
        p##3 = *(const f32x4*)(s_ + 12);                                       \
        p##4 = *(const f32x4*)(s_ + 16);                                       \
        p##5 = *(const f32x4*)(s_ + 20);                                       \
        p##6 = *(const f32x4*)(s_ + 24);                                       \
        p##7 = *(const f32x4*)(s_ + 28);                                       \
    }

#define CVTW(p, BUF)                                                           \
    {                                                                          \
        union { short8 v; uint32_t u[4]; } w0_, w1_, w2_, w3_;                 \
        asm("v_cvt_pk_bf16_f32 %0, %1, %2" : "=v"(w0_.u[0]) : "v"(p##0[0]), "v"(p##0[1])); \
        asm("v_cvt_pk_bf16_f32 %0, %1, %2" : "=v"(w0_.u[1]) : "v"(p##0[2]), "v"(p##0[3])); \
        asm("v_cvt_pk_bf16_f32 %0, %1, %2" : "=v"(w0_.u[2]) : "v"(p##1[0]), "v"(p##1[1])); \
        asm("v_cvt_pk_bf16_f32 %0, %1, %2" : "=v"(w0_.u[3]) : "v"(p##1[2]), "v"(p##1[3])); \
        asm("v_cvt_pk_bf16_f32 %0, %1, %2" : "=v"(w1_.u[0]) : "v"(p##2[0]), "v"(p##2[1])); \
        asm("v_cvt_pk_bf16_f32 %0, %1, %2" : "=v"(w1_.u[1]) : "v"(p##2[2]), "v"(p##2[3])); \
        asm("v_cvt_pk_bf16_f32 %0, %1, %2" : "=v"(w1_.u[2]) : "v"(p##3[0]), "v"(p##3[1])); \
        asm("v_cvt_pk_bf16_f32 %0, %1, %2" : "=v"(w1_.u[3]) : "v"(p##3[2]), "v"(p##3[3])); \
        asm("v_cvt_pk_bf16_f32 %0, %1, %2" : "=v"(w2_.u[0]) : "v"(p##4[0]), "v"(p##4[1])); \
        asm("v_cvt_pk_bf16_f32 %0, %1, %2" : "=v"(w2_.u[1]) : "v"(p##4[2]), "v"(p##4[3])); \
        asm("v_cvt_pk_bf16_f32 %0, %1, %2" : "=v"(w2_.u[2]) : "v"(p##5[0]), "v"(p##5[1])); \
        asm("v_cvt_pk_bf16_f32 %0, %1, %2" : "=v"(w2_.u[3]) : "v"(p##5[2]), "v"(p##5[3])); \
        asm("v_cvt_pk_bf16_f32 %0, %1, %2" : "=v"(w3_.u[0]) : "v"(p##6[0]), "v"(p##6[1])); \
        asm("v_cvt_pk_bf16_f32 %0, %1, %2" : "=v"(w3_.u[1]) : "v"(p##6[2]), "v"(p##6[3])); \
        asm("v_cvt_pk_bf16_f32 %0, %1, %2" : "=v"(w3_.u[2]) : "v"(p##7[0]), "v"(p##7[1])); \
        asm("v_cvt_pk_bf16_f32 %0, %1, %2" : "=v"(w3_.u[3]) : "v"(p##7[2]), "v"(p##7[3])); \
        *(short8*)&Ab[BUF][swr0] = w0_.v;                                      \
        *(short8*)&Ab[BUF][swr1] = w1_.v;                                      \
        *(short8*)&Ab[BUF][swr2] = w2_.v;                                      \
        *(short8*)&Ab[BUF][swr3] = w3_.v;                                      \
    }

    // prologue: tile0 -> Ab[0]/Bb[0]; tile1 A -> Q (regs only)
    LOADA(P, 0);
    stageB(0, 0);
    CVTW(P, 0);          // waits tile0 A loads (once)
    LOADA(Q, 1);
    __syncthreads();

    for (int kt = 0; kt < NKT; kt += 2) {
        // phase kt: compute buf0 (tile kt); A(kt+1) is in Q
        if (kt + 2 < NKT) LOADA(P, kt + 2);
        stageB(1, kt + 1);          // B for tile kt+1 -> Bb[1]
        compute(0);
        CVTW(Q, 1);                 // A for tile kt+1 -> Ab[1] (regs pre-drained)
        __syncthreads();

        // phase kt+1: compute buf1 (tile kt+1); A(kt+2) is in P
        if (kt + 3 < NKT) LOADA(Q, kt + 3);
        if (kt + 2 < NKT) stageB(0, kt + 2);
        compute(1);
        if (kt + 2 < NKT) CVTW(P, 0);
        __syncthreads();
    }
#undef LOADA
#undef CVTW

    // epilogue: C row = wm + i*16 + (lane>>4)*4 + r ; col = wn + j*16 + (lane&15)
    const float* bptr = bias + nb * 128;
    float* obase = out + (size_t)nb * OUT_SEG;
    #pragma unroll
    for (int i = 0; i < 4; ++i) {
        int mloc = wm + i * 16 + (lane >> 4) * 4;
        #pragma unroll
        for (int j = 0; j < 4; ++j) {
            int g = wn + j * 16 + lr;
            float bv = bptr[g];
            #pragma unroll
            for (int rr = 0; rr < 4; ++rr) {
                int mo = m0 + mloc + rr;
                if (mo < M_TOT) obase[(size_t)mo * G_ + g] = acc[i][j][rr] + bv;
            }
        }
    }
}

// ---------------- KL reduction: stage 1 (per-block partials, no atomics) -----
__global__ __launch_bounds__(256) void kl_kernel(const float* __restrict__ out,
                                                 float* __restrict__ partial)
{
    int wid  = threadIdx.x >> 6;
    int row  = blockIdx.x * 4 + wid;        // M_TOT = 4092*4 exactly
    int lane = threadIdx.x & 63;
    const float* zm  = out;
    const float* zlv = out + OUT_SEG;
    const float* qm  = out + (size_t)2 * OUT_SEG;
    const float* qlv = out + (size_t)3 * OUT_SEG;
    size_t base = (size_t)row * G_;
    float s = 0.f;
    #pragma unroll
    for (int hh = 0; hh < 2; ++hh) {
        int g = lane + hh * 64;
        float a = zm[base + g], b = zlv[base + g];
        float c = qm[base + g], d = qlv[base + g];
        float diff = a - c;
        s += d - b + (__expf(b) + diff * diff) * __expf(-d) - 1.0f;
    }
    #pragma unroll
    for (int off = 32; off > 0; off >>= 1)
        s += __shfl_down(s, off);
    __shared__ float pw[4];
    if (lane == 0) pw[wid] = s;
    __syncthreads();
    if (threadIdx.x == 0)
        partial[blockIdx.x] = pw[0] + pw[1] + pw[2] + pw[3];
}

// ---------------- KL reduction: stage 2 --------------------------------------
__global__ __launch_bounds__(256) void kl_final(const float* __restrict__ partial,
                                                float* __restrict__ out)
{
    float s = 0.f;
    for (int i = threadIdx.x; i < KL_BLOCKS; i += 256) s += partial[i];
    #pragma unroll
    for (int off = 32; off > 0; off >>= 1)
        s += __shfl_down(s, off);
    __shared__ float pw[4];
    int wid = threadIdx.x >> 6;
    int lane = threadIdx.x & 63;
    if (lane == 0) pw[wid] = s;
    __syncthreads();
    if (threadIdx.x == 0)
        out[KL_IDX] = 0.5f * (pw[0] + pw[1] + pw[2] + pw[3]) / (float)M_TOT;
}

// ---------------- launcher ----------------------------------------------------
extern "C" void kernel_launch(void* const* d_in, const int* in_sizes, int n_in,
                              void* d_out, int out_size, void* d_ws, size_t ws_size,
                              hipStream_t stream)
{
    const float* events   = (const float*)d_in[0];
    const float* contexts = (const float*)d_in[1];
    const float* Wzm = (const float*)d_in[2];
    const float* bzm = (const float*)d_in[3];
    const float* Wzv = (const float*)d_in[4];
    const float* bzv = (const float*)d_in[5];
    const float* Wqm = (const float*)d_in[6];
    const float* bqm = (const float*)d_in[7];
    const float* Wqv = (const float*)d_in[8];
    const float* bqv = (const float*)d_in[9];
    float* out = (float*)d_out;

    u16*   wt      = (u16*)((char*)d_ws + WS_WT_OFF);
    float* bias    = (float*)((char*)d_ws + WS_BIAS_OFF);
    float* partial = (float*)((char*)d_ws + WS_PART_OFF);

    prep_kernel<<<512, 256, 0, stream>>>(Wzm, bzm, Wzv, bzv, Wqm, bqm, Wqv, bqv,
                                         wt, bias);
    gemm_kernel<<<512, 256, 0, stream>>>(events, contexts, wt, bias, out);
    kl_kernel<<<KL_BLOCKS, 256, 0, stream>>>(out, partial);
    kl_final<<<1, 256, 0, stream>>>(partial, out);
}

// Round 7
// 129.178 us; speedup vs baseline: 2.7298x; 1.2117x over previous
//
#include <hip/hip_runtime.h>
#include <stdint.h>

typedef unsigned short u16;
typedef __attribute__((ext_vector_type(8))) short short8;
typedef __attribute__((ext_vector_type(4))) float f32x4;

#define B_      16
#define L_      1024
#define H_      1024
#define G_      128
#define M_TOT   16368            // B*(L-1)
#define K_TOT   3072
#define OUT_SEG 2095104          // M_TOT*G_
#define KL_IDX  (4*OUT_SEG)
#define KL_BLOCKS 4092           // M_TOT / 4 exactly
#define NKT     96               // K_TOT / 32

// ws layout
#define WS_WT_OFF    0           // bf16 W'T [512][3072] = 3,145,728 B
#define WS_BIAS_OFF  3145728     // float[512]
#define WS_PART_OFF  3147776     // float[4092] block partials

__device__ inline u16 f2bf(float f) {
    union { float f; uint32_t u; } x; x.f = f;
    uint32_t u = x.u;
    return (u16)((u + 0x7fffu + ((u >> 16) & 1u)) >> 16);
}

__device__ inline void gload16(const void* g, void* l) {
    __builtin_amdgcn_global_load_lds(
        (const __attribute__((address_space(1))) void*)g,
        (__attribute__((address_space(3))) void*)l, 16, 0, 0);
}

// ---------------- prep: build W'T (bf16, [512][3072]) + bias[512] ------------
__global__ __launch_bounds__(256) void prep_kernel(
    const float* __restrict__ Wzm, const float* __restrict__ bzm,
    const float* __restrict__ Wzv, const float* __restrict__ bzv,
    const float* __restrict__ Wqm, const float* __restrict__ bqm,
    const float* __restrict__ Wqv, const float* __restrict__ bqv,
    u16* __restrict__ wt, float* __restrict__ bias)
{
    int n = blockIdx.x;                 // 0..511 (output column)
    int tid = threadIdx.x;
    const float* W; const float* bsrc; int g; int kmax;
    if (n < 128)      { W = Wzm; bsrc = bzm; g = n;       kmax = 2048; }
    else if (n < 256) { W = Wzv; bsrc = bzv; g = n - 128; kmax = 2048; }
    else if (n < 384) { W = Wqm; bsrc = bqm; g = n - 256; kmax = 3072; }
    else              { W = Wqv; bsrc = bqv; g = n - 384; kmax = 3072; }
    if (tid == 0) bias[n] = bsrc[g];
    #pragma unroll
    for (int i = 0; i < 12; ++i) {
        int k = i * 256 + tid;
        float v = (k < kmax) ? W[(size_t)k * G_ + g] : 0.0f;
        wt[(size_t)n * K_TOT + k] = f2bf(v);
    }
}

// ---------------- GEMM: out[m, 0:512] = ce @ W' + bias ----------------------
// BM=64, BN=128, BK=32, 128 threads = 2 waves, each wave 64x64.
// 1024 blocks -> 4 blocks/CU (LDS 24KB, VGPR<=128): TLP hides latency.
// A: global f32x4 -> named regs -> cvt_pk bf16 -> swizzled ds_write_b128.
// B: global_load_lds, source-preswizzled (linear LDS dest).
// Swizzle (4 slots of 16B per 64B row): slot ^= (row>>1)&3.
__global__ __launch_bounds__(128, 4) void gemm_kernel(
    const float* __restrict__ events, const float* __restrict__ contexts,
    const u16* __restrict__ wt, const float* __restrict__ bias,
    float* __restrict__ out)
{
    __shared__ u16 Ab[2][64 * 32];    // bf16 A tile, swizzled (4 KB each)
    __shared__ u16 Bb[2][128 * 32];   // bf16 B tile, swizzled (8 KB each)

    const int tid  = threadIdx.x;
    const int bid  = blockIdx.x;
    // XCD-aware swizzle: the 4 nb-blocks sharing an A panel land on one XCD.
    const int xcd  = bid & 7;
    const int nb   = (bid >> 3) & 3;
    const int mp   = xcd * 32 + (bid >> 5);   // 0..255
    const int m0   = mp * 64;

    const int lane = tid & 63;
    const int w    = tid >> 6;            // 0..1
    const int wn   = w * 64;
    const int lr   = lane & 15;
    const int ks   = lane >> 4;           // 16B k-slot 0..3

    // ---- A staging: row r = tid>>1 (0..63), half h = tid&1 (16 floats) ----
    const int r = tid >> 1;
    const int h = tid & 1;
    int m = m0 + r; if (m > M_TOT - 1) m = M_TOT - 1;
    int bb = m / 1023;
    int tt = m - bb * 1023;
    const float* pa0 = events   + ((size_t)(bb * L_ + tt)) * H_;
    const float* pa2 = contexts + ((size_t)(bb * (L_ - 1) + tt)) * H_;
    const int swr0 = r * 32 + ((((h << 1) + 0) ^ ((r >> 1) & 3)) << 3);
    const int swr1 = r * 32 + ((((h << 1) + 1) ^ ((r >> 1) & 3)) << 3);

    // ---- B staging: 4 gload_lds chunks/thread; slot swizzle is it-invariant:
    //   chunk c = it*128+tid -> row = it*32 + (tid>>2), slot = tid&3,
    //   src slot' = (tid&3) ^ ((tid>>3)&3)
    const int bslot = (tid & 3) ^ ((tid >> 3) & 3);
    const u16* bBbase = wt + (size_t)(nb * 128 + (tid >> 2)) * K_TOT + bslot * 8;

    // ---- fragment read offsets (u16), swizzled ----
    int aoff[4], boff[4];
    #pragma unroll
    for (int i = 0; i < 4; ++i) {
        int row = i * 16 + lr;
        aoff[i] = row * 32 + ((ks ^ ((row >> 1) & 3)) << 3);
        int nn  = wn + i * 16 + lr;
        boff[i] = nn * 32 + ((ks ^ ((nn >> 1) & 3)) << 3);
    }

    f32x4 acc[4][4];
    #pragma unroll
    for (int i = 0; i < 4; ++i)
        #pragma unroll
        for (int j = 0; j < 4; ++j)
            acc[i][j] = (f32x4){0.f, 0.f, 0.f, 0.f};

    auto stageB = [&](int buf, int kt) {
        int k0 = kt * 32;
        #pragma unroll
        for (int it = 0; it < 4; ++it)
            gload16(bBbase + (size_t)it * 32 * K_TOT + k0,
                    &Bb[buf][(it * 128 + tid) * 8]);
    };
    auto compute = [&](int buf) {
        short8 a[4], bf[4];
        #pragma unroll
        for (int i = 0; i < 4; ++i)
            a[i] = *(const short8*)&Ab[buf][aoff[i]];
        #pragma unroll
        for (int j = 0; j < 4; ++j)
            bf[j] = *(const short8*)&Bb[buf][boff[j]];
        #pragma unroll
        for (int i = 0; i < 4; ++i)
            #pragma unroll
            for (int j = 0; j < 4; ++j)
                acc[i][j] = __builtin_amdgcn_mfma_f32_16x16x32_bf16(
                    a[i], bf[j], acc[i][j], 0, 0, 0);
    };

    // Named A-staging regs (1-deep; TLP from 4 blocks/CU hides the latency)
    f32x4 P0, P1, P2, P3;

#define LOADA(KT)                                                              \
    {                                                                          \
        int k0_ = (KT) * 32;                                                   \
        int rg_ = k0_ >> 10;                                                   \
        int kq_ = (k0_ & 1023) + h * 16;                                       \
        const float* s_ = (rg_ == 0) ? pa0 : ((rg_ == 1) ? (pa0 + H_) : pa2);  \
        s_ += kq_;                                                             \
        P0 = *(const f32x4*)(s_ +  0);                                         \
        P1 = *(const f32x4*)(s_ +  4);                                         \
        P2 = *(const f32x4*)(s_ +  8);                                         \
        P3 = *(const f32x4*)(s_ + 12);                                         \
    }

#define CVTW(BUF)                                                              \
    {                                                                          \
        union { short8 v; uint32_t u[4]; } w0_, w1_;                           \
        asm("v_cvt_pk_bf16_f32 %0, %1, %2" : "=v"(w0_.u[0]) : "v"(P0[0]), "v"(P0[1])); \
        asm("v_cvt_pk_bf16_f32 %0, %1, %2" : "=v"(w0_.u[1]) : "v"(P0[2]), "v"(P0[3])); \
        asm("v_cvt_pk_bf16_f32 %0, %1, %2" : "=v"(w0_.u[2]) : "v"(P1[0]), "v"(P1[1])); \
        asm("v_cvt_pk_bf16_f32 %0, %1, %2" : "=v"(w0_.u[3]) : "v"(P1[2]), "v"(P1[3])); \
        asm("v_cvt_pk_bf16_f32 %0, %1, %2" : "=v"(w1_.u[0]) : "v"(P2[0]), "v"(P2[1])); \
        asm("v_cvt_pk_bf16_f32 %0, %1, %2" : "=v"(w1_.u[1]) : "v"(P2[2]), "v"(P2[3])); \
        asm("v_cvt_pk_bf16_f32 %0, %1, %2" : "=v"(w1_.u[2]) : "v"(P3[0]), "v"(P3[1])); \
        asm("v_cvt_pk_bf16_f32 %0, %1, %2" : "=v"(w1_.u[3]) : "v"(P3[2]), "v"(P3[3])); \
        *(short8*)&Ab[BUF][swr0] = w0_.v;                                      \
        *(short8*)&Ab[BUF][swr1] = w1_.v;                                      \
    }

    // prologue: fill buffer 0
    LOADA(0);
    stageB(0, 0);
    CVTW(0);
    __syncthreads();

    int cur = 0;
    for (int kt = 0; kt < NKT; ++kt) {
        if (kt + 1 < NKT) {
            LOADA(kt + 1);             // A global->reg for next tile (issue)
            stageB(cur ^ 1, kt + 1);   // async B loads for next tile
        }
        compute(cur);                  // 8 ds_read + 16 MFMA
        if (kt + 1 < NKT) CVTW(cur ^ 1);   // cvt + swizzled ds_write
        __syncthreads();
        cur ^= 1;
    }
#undef LOADA
#undef CVTW

    // epilogue: C row = i*16 + (lane>>4)*4 + rr ; col = wn + j*16 + (lane&15)
    const float* bptr = bias + nb * 128;
    float* obase = out + (size_t)nb * OUT_SEG;
    #pragma unroll
    for (int i = 0; i < 4; ++i) {
        int mloc = i * 16 + (lane >> 4) * 4;
        #pragma unroll
        for (int j = 0; j < 4; ++j) {
            int gg = wn + j * 16 + lr;
            float bv = bptr[gg];
            #pragma unroll
            for (int rr = 0; rr < 4; ++rr) {
                int mo = m0 + mloc + rr;
                if (mo < M_TOT) obase[(size_t)mo * G_ + gg] = acc[i][j][rr] + bv;
            }
        }
    }
}

// ---------------- KL reduction: stage 1 (per-block partials, no atomics) -----
__global__ __launch_bounds__(256) void kl_kernel(const float* __restrict__ out,
                                                 float* __restrict__ partial)
{
    int wid  = threadIdx.x >> 6;
    int row  = blockIdx.x * 4 + wid;        // M_TOT = 4092*4 exactly
    int lane = threadIdx.x & 63;
    const float* zm  = out;
    const float* zlv = out + OUT_SEG;
    const float* qm  = out + (size_t)2 * OUT_SEG;
    const float* qlv = out + (size_t)3 * OUT_SEG;
    size_t base = (size_t)row * G_;
    float s = 0.f;
    #pragma unroll
    for (int hh = 0; hh < 2; ++hh) {
        int g = lane + hh * 64;
        float a = zm[base + g], b = zlv[base + g];
        float c = qm[base + g], d = qlv[base + g];
        float diff = a - c;
        s += d - b + (__expf(b) + diff * diff) * __expf(-d) - 1.0f;
    }
    #pragma unroll
    for (int off = 32; off > 0; off >>= 1)
        s += __shfl_down(s, off);
    __shared__ float pw[4];
    if (lane == 0) pw[wid] = s;
    __syncthreads();
    if (threadIdx.x == 0)
        partial[blockIdx.x] = pw[0] + pw[1] + pw[2] + pw[3];
}

// ---------------- KL reduction: stage 2 --------------------------------------
__global__ __launch_bounds__(256) void kl_final(const float* __restrict__ partial,
                                                float* __restrict__ out)
{
    float s = 0.f;
    for (int i = threadIdx.x; i < KL_BLOCKS; i += 256) s += partial[i];
    #pragma unroll
    for (int off = 32; off > 0; off >>= 1)
        s += __shfl_down(s, off);
    __shared__ float pw[4];
    int wid = threadIdx.x >> 6;
    int lane = threadIdx.x & 63;
    if (lane == 0) pw[wid] = s;
    __syncthreads();
    if (threadIdx.x == 0)
        out[KL_IDX] = 0.5f * (pw[0] + pw[1] + pw[2] + pw[3]) / (float)M_TOT;
}

// ---------------- launcher ----------------------------------------------------
extern "C" void kernel_launch(void* const* d_in, const int* in_sizes, int n_in,
                              void* d_out, int out_size, void* d_ws, size_t ws_size,
                              hipStream_t stream)
{
    const float* events   = (const float*)d_in[0];
    const float* contexts = (const float*)d_in[1];
    const float* Wzm = (const float*)d_in[2];
    const float* bzm = (const float*)d_in[3];
    const float* Wzv = (const float*)d_in[4];
    const float* bzv = (const float*)d_in[5];
    const float* Wqm = (const float*)d_in[6];
    const float* bqm = (const float*)d_in[7];
    const float* Wqv = (const float*)d_in[8];
    const float* bqv = (const float*)d_in[9];
    float* out = (float*)d_out;

    u16*   wt      = (u16*)((char*)d_ws + WS_WT_OFF);
    float* bias    = (float*)((char*)d_ws + WS_BIAS_OFF);
    float* partial = (float*)((char*)d_ws + WS_PART_OFF);

    prep_kernel<<<512, 256, 0, stream>>>(Wzm, bzm, Wzv, bzv, Wqm, bqm, Wqv, bqv,
                                         wt, bias);
    gemm_kernel<<<1024, 128, 0, stream>>>(events, contexts, wt, bias, out);
    kl_kernel<<<KL_BLOCKS, 256, 0, stream>>>(out, partial);
    kl_final<<<1, 256, 0, stream>>>(partial, out);
}